// Round 20
// baseline (2451.945 us; speedup 1.0000x reference)
//
#include <hip/hip_runtime.h>
#include <cmath>

// Memory_76957224010242: 100-step Adam inference loop.
// G = W^T W, u = (x-c)@W once; per-iter s = r@G fused with Adam + loss.
// R20: A-operand (rbf) moves from LDS-staging to direct global->VGPR fragment
// loads (per-wave-private, 2-deep prefetch, 3-slot rotation). B (G) stays
// LDS-staged (2-buf, group-local). Cuts LDS port traffic 1.65 -> 0.9 MB/iter
// (the R19 floor). vmcnt(4) counted waits; sched_barrier-pinned issue groups.

#define B_SZ 512
#define H_SZ 2048
#define D_SZ 4096
#define ITERS 100

typedef __attribute__((ext_vector_type(8))) short short8;
typedef __attribute__((ext_vector_type(4))) float f32x4;

__device__ __forceinline__ unsigned short f2bf(float f) {
    unsigned u = __float_as_uint(f);
    u = (u + 0x7fffu + ((u >> 16) & 1u)) >> 16;  // RNE
    return (unsigned short)u;
}
__device__ __forceinline__ float bflo(unsigned mv) { return __uint_as_float(mv << 16); }
__device__ __forceinline__ float bfhi(unsigned mv) { return __uint_as_float(mv & 0xffff0000u); }

__device__ __forceinline__ void gload_lds16(const unsigned short* g, unsigned short* l) {
    __builtin_amdgcn_global_load_lds((const __attribute__((address_space(1))) void*)g,
                                     (__attribute__((address_space(3))) void*)l, 16, 0, 0);
}

// ---- W (D,H) f32 -> Wt (H,D) bf16 (transpose + cast) ----
__global__ __launch_bounds__(256) void k_transpose(const float* __restrict__ W,
                                                   unsigned short* __restrict__ Wt) {
    __shared__ unsigned short tile[64][72];
    const int d0 = blockIdx.x * 64, h0 = blockIdx.y * 64;
    const int t = threadIdx.x;
    const int lr = t >> 6, lc = t & 63;
#pragma unroll
    for (int rr = 0; rr < 16; ++rr) {
        const int dl = rr * 4 + lr;
        tile[dl][lc] = f2bf(W[(size_t)(d0 + dl) * H_SZ + h0 + lc]);
    }
    __syncthreads();
#pragma unroll
    for (int rr = 0; rr < 16; ++rr) {
        const int hl = rr * 4 + lr;
        Wt[(size_t)(h0 + hl) * D_SZ + d0 + lc] = tile[lc][hl];
    }
}

// ---- xc = (x - c) bf16, xc2[b] = sum_d (x-c)^2 ----
__global__ __launch_bounds__(256) void k_prepx(const float* __restrict__ x, const float* __restrict__ c,
                                               unsigned short* __restrict__ xcbf, float* __restrict__ xc2) {
    const int b = blockIdx.x, t = threadIdx.x;
    const float* xr = x + (size_t)b * D_SZ;
    unsigned short* orow = xcbf + (size_t)b * D_SZ;
    float acc = 0.f;
#pragma unroll
    for (int ch = 0; ch < 2; ++ch) {
        const int base = (ch * 256 + t) * 8;
        const float4 v0 = *(const float4*)(xr + base);
        const float4 v1 = *(const float4*)(xr + base + 4);
        const float4 c0 = *(const float4*)(c + base);
        const float4 c1 = *(const float4*)(c + base + 4);
        const float e0 = v0.x - c0.x, e1 = v0.y - c0.y, e2 = v0.z - c0.z, e3 = v0.w - c0.w;
        const float e4 = v1.x - c1.x, e5 = v1.y - c1.y, e6 = v1.z - c1.z, e7 = v1.w - c1.w;
        acc += e0 * e0 + e1 * e1 + e2 * e2 + e3 * e3 + e4 * e4 + e5 * e5 + e6 * e6 + e7 * e7;
        short8 ov;
        ov[0] = (short)f2bf(e0); ov[1] = (short)f2bf(e1); ov[2] = (short)f2bf(e2); ov[3] = (short)f2bf(e3);
        ov[4] = (short)f2bf(e4); ov[5] = (short)f2bf(e5); ov[6] = (short)f2bf(e6); ov[7] = (short)f2bf(e7);
        *(short8*)(orow + base) = ov;
    }
#pragma unroll
    for (int off = 32; off > 0; off >>= 1) acc += __shfl_down(acc, off);
    __shared__ float wred[4];
    if ((t & 63) == 0) wred[t >> 6] = acc;
    __syncthreads();
    if (t == 0) xc2[b] = wred[0] + wred[1] + wred[2] + wred[3];
}

// ---- permuted-layout init: r (perm), mv = 0, rbfA = bf16(r0) row-major ----
// perm index for (row, col): ((row>>2)*H + col)*4 + (row&3)
__global__ __launch_bounds__(256) void k_init(const float* __restrict__ r0, float* __restrict__ rp,
                                              unsigned* __restrict__ mv,
                                              unsigned short* __restrict__ rbfA) {
    const size_t i = (size_t)blockIdx.x * 256 + threadIdx.x;
#pragma unroll
    for (int k = 0; k < 4; ++k) {
        const size_t idx = i + (size_t)k * 262144;
        const float val = r0[idx];
        const int row = (int)(idx >> 11), col = (int)(idx & (H_SZ - 1));
        rp[(((size_t)(row >> 2) * H_SZ + col) << 2) + (row & 3)] = val;
        mv[idx] = 0u;                 // zeros: layout-agnostic
        rbfA[idx] = f2bf(val);        // row-major (GEMM A operand)
    }
}

// ---- one-time TM x 64 tile bf16 MFMA GEMM.
// EPI 0: store bf16 row-major (G). EPI 1: store f32 PERMUTED float4 (u).
template <int TM, int EPI>
__global__ __launch_bounds__(256) void gemm64(
        const unsigned short* __restrict__ A, int lda,
        const unsigned short* __restrict__ Bt, int ldb, int K,
        unsigned short* __restrict__ Cb, float* __restrict__ Cf, int ldc) {
    __shared__ alignas(16) unsigned short Al[2][TM * 64];
    __shared__ alignas(16) unsigned short Bl[2][64 * 64];
    const int t = threadIdx.x, w = t >> 6, lane = t & 63;
    const int m0 = blockIdx.y * TM, n0 = blockIdx.x * 64;
    constexpr int NJ = (TM == 64) ? 2 : 1;
    const int row_base = (TM == 64) ? (w >> 1) * 32 : 0;
    const int col_base = (TM == 64) ? (w & 1) * 32 : w * 16;

    f32x4 acc[2][NJ] = {};

    auto stage = [&](int buf, int k0) {
#pragma unroll
        for (int h = 0; h < 2; ++h) {
            const int c = h * 256 + t;
            const int row = c >> 3, g = c & 7;
            const int gl = g ^ (row & 7);
            gload_lds16(Bt + (size_t)(n0 + row) * ldb + k0 + gl * 8, &Bl[buf][(h * 256 + w * 64) * 8]);
        }
        if constexpr (TM == 64) {
#pragma unroll
            for (int h = 0; h < 2; ++h) {
                const int c = h * 256 + t;
                const int row = c >> 3, g = c & 7;
                const int gl = g ^ (row & 7);
                gload_lds16(A + (size_t)(m0 + row) * lda + k0 + gl * 8, &Al[buf][(h * 256 + w * 64) * 8]);
            }
        } else {
            const int row = t >> 3, g = t & 7;
            const int gl = g ^ (row & 7);
            gload_lds16(A + (size_t)(m0 + row) * lda + k0 + gl * 8, &Al[buf][(w * 64) * 8]);
        }
    };

    stage(0, 0);
    const int nK = K >> 6;
    for (int kt = 0; kt < nK; ++kt) {
        __syncthreads();
        const int cur = kt & 1;
        if (kt + 1 < nK) stage(cur ^ 1, (kt + 1) << 6);
        const unsigned short* a_base = Al[cur];
        const unsigned short* b_base = Bl[cur];
#pragma unroll
        for (int kh = 0; kh < 2; ++kh) {
            short8 av[2], bv[NJ];
#pragma unroll
            for (int i = 0; i < 2; ++i) {
                const int row = row_base + i * 16 + (lane & 15);
                const int g = (kh * 4 + (lane >> 4)) ^ (row & 7);
                av[i] = *(const short8*)(a_base + row * 64 + g * 8);
            }
#pragma unroll
            for (int j = 0; j < NJ; ++j) {
                const int row = col_base + j * 16 + (lane & 15);
                const int g = (kh * 4 + (lane >> 4)) ^ (row & 7);
                bv[j] = *(const short8*)(b_base + row * 64 + g * 8);
            }
#pragma unroll
            for (int i = 0; i < 2; ++i)
#pragma unroll
                for (int j = 0; j < NJ; ++j)
                    acc[i][j] = __builtin_amdgcn_mfma_f32_16x16x32_bf16(av[i], bv[j], acc[i][j], 0, 0, 0);
        }
    }

#pragma unroll
    for (int i = 0; i < 2; ++i)
#pragma unroll
        for (int j = 0; j < NJ; ++j) {
            const int col = n0 + col_base + j * 16 + (lane & 15);
            const int row0 = m0 + row_base + i * 16 + ((lane >> 4) << 2);
            if constexpr (EPI == 0) {
#pragma unroll
                for (int q = 0; q < 4; ++q)
                    Cb[(size_t)(row0 + q) * ldc + col] = f2bf(acc[i][j][q]);
            } else {
                float4 st;
                st.x = acc[i][j][0]; st.y = acc[i][j][1]; st.z = acc[i][j][2]; st.w = acc[i][j][3];
                *(float4*)(Cf + (((size_t)(row0 >> 2) * ldc + col) << 2)) = st;
            }
        }
}

// ---- loop kernel: A direct-to-reg (2-deep, 3-slot), B LDS-staged (2-buf).
// 64x64 tile, 16 waves, 256 blocks. Wave = (quadrant qd = w&3) x (K-group gr = w>>2).
__global__ __launch_bounds__(1024) void gemm_q(
        const unsigned short* __restrict__ Ain,   // bf16 r in (B_SZ x H), row-major
        const unsigned short* __restrict__ G,     // bf16 G (H x H), row-major
        float* __restrict__ rp,                   // f32 r, PERMUTED [row/4][col][4]
        unsigned* __restrict__ mv,                // packed m|v, PERMUTED
        const float* __restrict__ up,             // u, PERMUTED
        const float* __restrict__ bvec,
        unsigned short* __restrict__ rbf_out,     // row-major; null on last iter
        float* __restrict__ out_r,                // row-major d_out (last iter only)
        float* __restrict__ lossPart,
        float inv1, float inv2) {
    __shared__ alignas(16) unsigned short Bb[2][4][4096];  // 64 KB: B, 2-buf x 4 groups
    __shared__ float scr[17408];                           // 68 KB: K-reduction scratch
    __shared__ float wred[16];
    const int t = threadIdx.x, w = t >> 6, lane = t & 63;
    const int bid = blockIdx.x;
    const int m0 = (bid >> 5) * 64;
    const int n0 = ((bid & 7) * 4 + ((bid >> 3) & 3)) * 64;   // XCD-pinned G panels
    const int qd = w & 3, gr = w >> 2;
    const int qrow = (qd >> 1) * 32, qcol = (qd & 1) * 32;
    const int rlo = lane & 15, hi = lane >> 4;

    // ---- epilogue-state prefetch: 4 VMEM issues (oldest in FIFO) ----
    const int col0 = n0 + qcol + (gr & 1) * 16 + rlo;
    const int rowb = m0 + qrow + (gr >> 1) * 16 + (hi << 2);   // 4-aligned
    const size_t pidx = ((size_t)(rowb >> 2) * H_SZ + col0) << 2;
    const float pre_b = bvec[col0];
    const float4 pre_r = *(const float4*)(rp + pidx);
    const float4 pre_u = *(const float4*)(up + pidx);
    const uint4 pre_mv = *(const uint4*)(mv + pidx);
    __builtin_amdgcn_sched_barrier(0);

    // ---- B staging (group-local, source XOR-swizzled) ----
    const int tt = t & 255;
    auto stageB = [&](int buf, int s) {
        const int kbase = gr * 512 + s * 64;
#pragma unroll
        for (int c = 0; c < 2; ++c) {
            const int idx = c * 256 + tt;
            const int row = idx >> 3, g = idx & 7;
            const int gl = g ^ (row & 7);
            gload_lds16(G + (size_t)(n0 + row) * H_SZ + kbase + gl * 8, &Bb[buf][gr][idx * 8]);
        }
    };

    // ---- A fragment loads: direct global->VGPR, fragment layout, no swizzle.
    // av[i][kh] = Ain[m0+qrow+i*16+rlo][gr*512 + s*64 + (kh*4+hi)*8 .. +8]
    const unsigned short* abase = Ain + (size_t)(m0 + qrow + rlo) * H_SZ + gr * 512 + hi * 8;
    short8 aF[3][2][2];
    auto loadA = [&](int slot, int s) {
#pragma unroll
        for (int i = 0; i < 2; ++i)
#pragma unroll
            for (int kh = 0; kh < 2; ++kh)
                aF[slot][i][kh] = *(const short8*)(abase + (size_t)i * 16 * H_SZ + s * 64 + kh * 32);
    };

    // prologue FIFO: [epi(4)] [B0(2)] [A0(4)] [A1(4)]
    stageB(0, 0);
    __builtin_amdgcn_sched_barrier(0);
    loadA(0, 0);
    __builtin_amdgcn_sched_barrier(0);
    loadA(1, 1);
    __builtin_amdgcn_sched_barrier(0);

    f32x4 acc[2][2] = {};
#pragma unroll
    for (int s = 0; s < 8; ++s) {
        // steady: drain A(s)+B(s) (and epi at s=0), leave A(s+2)'s 4 loads.
        if (s < 7) asm volatile("s_waitcnt vmcnt(4) lgkmcnt(0)" ::: "memory");
        else       asm volatile("s_waitcnt vmcnt(0) lgkmcnt(0)" ::: "memory");
        __builtin_amdgcn_s_barrier();
        __builtin_amdgcn_sched_barrier(0);
        if (s + 1 < 8) stageB((s + 1) & 1, s + 1);
        __builtin_amdgcn_sched_barrier(0);
        if (s + 2 < 8) loadA((s + 2) % 3, s + 2);
        __builtin_amdgcn_sched_barrier(0);
        const unsigned short* b_base = Bb[s & 1][gr];
#pragma unroll
        for (int kh = 0; kh < 2; ++kh) {
            short8 bv[2];
#pragma unroll
            for (int j = 0; j < 2; ++j) {
                const int row = qcol + j * 16 + rlo;
                bv[j] = *(const short8*)(b_base + row * 64 + ((kh * 4 + hi) ^ (row & 7)) * 8);
            }
#pragma unroll
            for (int i = 0; i < 2; ++i)
#pragma unroll
                for (int j = 0; j < 2; ++j)
                    acc[i][j] = __builtin_amdgcn_mfma_f32_16x16x32_bf16(aF[s % 3][i][kh], bv[j], acc[i][j], 0, 0, 0);
        }
    }

    // ---- K-reduction via LDS scratch (stride 17: gcd(17,32)=1) ----
    __syncthreads();
    const int wbase = (w * 64 + lane) * 17;
#pragma unroll
    for (int i = 0; i < 2; ++i)
#pragma unroll
        for (int j = 0; j < 2; ++j)
#pragma unroll
            for (int q = 0; q < 4; ++q)
                scr[wbase + (i * 2 + j) * 4 + q] = acc[i][j][q];
    __syncthreads();

    float sval[4];
#pragma unroll
    for (int q = 0; q < 4; ++q) {
        float s = 0.f;
#pragma unroll
        for (int g = 0; g < 4; ++g)
            s += scr[((g * 4 + qd) * 64 + lane) * 17 + gr * 4 + q];
        sval[q] = s;
    }

    // ---- fused Adam + loss (state in registers; vector stores) ----
    const float prer[4] = {pre_r.x, pre_r.y, pre_r.z, pre_r.w};
    const float preu[4] = {pre_u.x, pre_u.y, pre_u.z, pre_u.w};
    const unsigned premv[4] = {pre_mv.x, pre_mv.y, pre_mv.z, pre_mv.w};
    float lpart = 0.f;
    float rn4[4];
    unsigned mv4[4];
#pragma unroll
    for (int q = 0; q < 4; ++q) {
        const float s = sval[q];
        const float rold = prer[q];
        const float ue = preu[q];
        const float g = (2.0f / B_SZ) * (rold - pre_b - ue + s);
        lpart += (rold - pre_b) * (rold - pre_b) + rold * (s - 2.0f * ue);
        const float m1 = 0.9f * bflo(premv[q]) + 0.1f * g;
        const float v1 = 0.999f * bfhi(premv[q]) + 0.001f * (g * g);
        mv4[q] = (unsigned)f2bf(m1) | ((unsigned)f2bf(v1) << 16);
        rn4[q] = rold - 0.01f * (m1 * inv1) / (sqrtf(v1 * inv2) + 1e-8f);
    }
    *(uint4*)(mv + pidx) = make_uint4(mv4[0], mv4[1], mv4[2], mv4[3]);
    if (rbf_out) {
        *(float4*)(rp + pidx) = make_float4(rn4[0], rn4[1], rn4[2], rn4[3]);
#pragma unroll
        for (int q = 0; q < 4; ++q)
            rbf_out[(size_t)(rowb + q) * H_SZ + col0] = f2bf(rn4[q]);
    } else {
#pragma unroll
        for (int q = 0; q < 4; ++q)
            out_r[(size_t)(rowb + q) * H_SZ + col0] = rn4[q];
    }
#pragma unroll
    for (int off = 32; off > 0; off >>= 1) lpart += __shfl_down(lpart, off);
    if (lane == 0) wred[w] = lpart;
    __syncthreads();
    if (t == 0) {
        float sum = 0.f;
#pragma unroll
        for (int k = 0; k < 16; ++k) sum += wred[k];
        lossPart[bid] = sum;
    }
}

// ---- losses[t] = (sum of 256 lossPart + sum_b xc2) / B ----
__global__ __launch_bounds__(256) void k_finalize(const float* __restrict__ lossPart,
                                                  const float* __restrict__ xc2, float* __restrict__ out) {
    const int it = blockIdx.x, t = threadIdx.x;
    float p = lossPart[it * 256 + t] + xc2[t] + xc2[t + 256];
#pragma unroll
    for (int off = 32; off > 0; off >>= 1) p += __shfl_down(p, off);
    __shared__ float wred[4];
    if ((t & 63) == 0) wred[t >> 6] = p;
    __syncthreads();
    if (t == 0) out[(size_t)B_SZ * H_SZ + it] = (wred[0] + wred[1] + wred[2] + wred[3]) * (1.0f / B_SZ);
}

extern "C" void kernel_launch(void* const* d_in, const int* in_sizes, int n_in,
                              void* d_out, int out_size, void* d_ws, size_t ws_size,
                              hipStream_t stream) {
    const float* x = (const float*)d_in[0];
    const float* W = (const float*)d_in[1];
    const float* cvec = (const float*)d_in[2];
    const float* bvec = (const float*)d_in[3];
    const float* r0 = (const float*)d_in[4];
    float* out = (float*)d_out;
    char* ws = (char*)d_ws;

    unsigned short* Wt = (unsigned short*)(ws);              // 16 MB   (H x D bf16)
    unsigned short* Gbf = (unsigned short*)(ws + 16777216);  // 8 MB    (H x H bf16)
    unsigned short* xcbf = (unsigned short*)(ws + 25165824); // 4 MB    (B x D bf16)
    float* u = (float*)(ws + 29360128);                      // 4 MB    (B x H f32, permuted)
    float* r = (float*)(ws + 33554432);                      // 4 MB    (permuted)
    unsigned* mv = (unsigned*)(ws + 37748736);               // 4 MB    (bf16 m|v packed, permuted)
    unsigned short* rbfA = (unsigned short*)(ws + 41943040); // 2 MB    (row-major)
    unsigned short* rbfB = (unsigned short*)(ws + 44040192); // 2 MB
    float* xc2 = (float*)(ws + 46137344);                    // 2 KB
    float* lossPart = (float*)(ws + 46139392);               // 100 KB (ITERS x 256)

    k_transpose<<<dim3(64, 32), 256, 0, stream>>>(W, Wt);
    k_prepx<<<512, 256, 0, stream>>>(x, cvec, xcbf, xc2);
    k_init<<<1024, 256, 0, stream>>>(r0, r, mv, rbfA);
    // G = Wt @ Wt^T (W^T W), M=N=2048, K=4096 (1024 blocks, 4/CU)
    gemm64<64, 0><<<dim3(32, 32), 256, 0, stream>>>(Wt, D_SZ, Wt, D_SZ, D_SZ, Gbf, nullptr, H_SZ);
    // u = (x-c) @ W, M=512, N=2048, K=4096 (512 blocks, 2/CU) -> permuted store
    gemm64<32, 1><<<dim3(32, 16), 256, 0, stream>>>(xcbf, D_SZ, Wt, D_SZ, D_SZ, nullptr, u, H_SZ);

    for (int it = 0; it < ITERS; ++it) {
        const float inv1 = (float)(1.0 / (1.0 - std::pow(0.9, (double)(it + 1))));
        const float inv2 = (float)(1.0 / (1.0 - std::pow(0.999, (double)(it + 1))));
        const unsigned short* rin_bf = (it & 1) ? rbfB : rbfA;
        unsigned short* rout_bf = (it + 1 < ITERS) ? ((it & 1) ? rbfA : rbfB) : nullptr;
        gemm_q<<<256, 1024, 0, stream>>>(rin_bf, Gbf, r, mv, u, bvec, rout_bf, out,
                                         lossPart + (size_t)it * 256, inv1, inv2);
    }
    k_finalize<<<ITERS, 256, 0, stream>>>(lossPart, xc2, out);
}

// Round 21
// 1519.626 us; speedup vs baseline: 1.6135x; 1.6135x over previous
//
#include <hip/hip_runtime.h>
#include <cmath>

// Memory_76957224010242: 100-step Adam inference loop.
// G = W^T W, u = (x-c)@W once; per-iter s = r@G fused with Adam + loss.
// R21: rbf stored FRAGMENT-BLOCKED ([row/16][col/32][lane][8], lane =
// ((col>>3)&3)*16 + (row&15)) so the A-operand loads are direct global->VGPR
// AND fully coalesced (R20's idea minus the uncoalesced-gather mistake).
// Removes A's LDS staging writes+reads (1.69 -> 0.96 MB/iter LDS traffic).
// B (G) stays LDS-staged 2-buf; pipeline = counted vmcnt(4), A 3-slot/2-deep.

#define B_SZ 512
#define H_SZ 2048
#define D_SZ 4096
#define ITERS 100

typedef __attribute__((ext_vector_type(8))) short short8;
typedef __attribute__((ext_vector_type(4))) float f32x4;

__device__ __forceinline__ unsigned short f2bf(float f) {
    unsigned u = __float_as_uint(f);
    u = (u + 0x7fffu + ((u >> 16) & 1u)) >> 16;  // RNE
    return (unsigned short)u;
}
__device__ __forceinline__ float bflo(unsigned mv) { return __uint_as_float(mv << 16); }
__device__ __forceinline__ float bfhi(unsigned mv) { return __uint_as_float(mv & 0xffff0000u); }

// fragment-blocked index for r-as-bf16: (row, col) -> flat
__device__ __forceinline__ size_t fidx(int row, int col) {
    return ((((size_t)(row >> 4) * 64 + (col >> 5)) * 64) + ((col >> 3) & 3) * 16 + (row & 15)) * 8
           + (col & 7);
}

__device__ __forceinline__ void gload_lds16(const unsigned short* g, unsigned short* l) {
    __builtin_amdgcn_global_load_lds((const __attribute__((address_space(1))) void*)g,
                                     (__attribute__((address_space(3))) void*)l, 16, 0, 0);
}

// ---- W (D,H) f32 -> Wt (H,D) bf16 (transpose + cast) ----
__global__ __launch_bounds__(256) void k_transpose(const float* __restrict__ W,
                                                   unsigned short* __restrict__ Wt) {
    __shared__ unsigned short tile[64][72];
    const int d0 = blockIdx.x * 64, h0 = blockIdx.y * 64;
    const int t = threadIdx.x;
    const int lr = t >> 6, lc = t & 63;
#pragma unroll
    for (int rr = 0; rr < 16; ++rr) {
        const int dl = rr * 4 + lr;
        tile[dl][lc] = f2bf(W[(size_t)(d0 + dl) * H_SZ + h0 + lc]);
    }
    __syncthreads();
#pragma unroll
    for (int rr = 0; rr < 16; ++rr) {
        const int hl = rr * 4 + lr;
        Wt[(size_t)(h0 + hl) * D_SZ + d0 + lc] = tile[lc][hl];
    }
}

// ---- xc = (x - c) bf16, xc2[b] = sum_d (x-c)^2 ----
__global__ __launch_bounds__(256) void k_prepx(const float* __restrict__ x, const float* __restrict__ c,
                                               unsigned short* __restrict__ xcbf, float* __restrict__ xc2) {
    const int b = blockIdx.x, t = threadIdx.x;
    const float* xr = x + (size_t)b * D_SZ;
    unsigned short* orow = xcbf + (size_t)b * D_SZ;
    float acc = 0.f;
#pragma unroll
    for (int ch = 0; ch < 2; ++ch) {
        const int base = (ch * 256 + t) * 8;
        const float4 v0 = *(const float4*)(xr + base);
        const float4 v1 = *(const float4*)(xr + base + 4);
        const float4 c0 = *(const float4*)(c + base);
        const float4 c1 = *(const float4*)(c + base + 4);
        const float e0 = v0.x - c0.x, e1 = v0.y - c0.y, e2 = v0.z - c0.z, e3 = v0.w - c0.w;
        const float e4 = v1.x - c1.x, e5 = v1.y - c1.y, e6 = v1.z - c1.z, e7 = v1.w - c1.w;
        acc += e0 * e0 + e1 * e1 + e2 * e2 + e3 * e3 + e4 * e4 + e5 * e5 + e6 * e6 + e7 * e7;
        short8 ov;
        ov[0] = (short)f2bf(e0); ov[1] = (short)f2bf(e1); ov[2] = (short)f2bf(e2); ov[3] = (short)f2bf(e3);
        ov[4] = (short)f2bf(e4); ov[5] = (short)f2bf(e5); ov[6] = (short)f2bf(e6); ov[7] = (short)f2bf(e7);
        *(short8*)(orow + base) = ov;
    }
#pragma unroll
    for (int off = 32; off > 0; off >>= 1) acc += __shfl_down(acc, off);
    __shared__ float wred[4];
    if ((t & 63) == 0) wred[t >> 6] = acc;
    __syncthreads();
    if (t == 0) xc2[b] = wred[0] + wred[1] + wred[2] + wred[3];
}

// ---- init: r permuted [row/4][col][row&3]; mv = 0; rbfA fragment-blocked ----
__global__ __launch_bounds__(256) void k_init(const float* __restrict__ r0, float* __restrict__ rp,
                                              unsigned* __restrict__ mv,
                                              unsigned short* __restrict__ rbfA) {
    const size_t i = (size_t)blockIdx.x * 256 + threadIdx.x;
#pragma unroll
    for (int k = 0; k < 4; ++k) {
        const size_t idx = i + (size_t)k * 262144;
        const float val = r0[idx];
        const int row = (int)(idx >> 11), col = (int)(idx & (H_SZ - 1));
        rp[(((size_t)(row >> 2) * H_SZ + col) << 2) + (row & 3)] = val;
        mv[idx] = 0u;
        rbfA[fidx(row, col)] = f2bf(val);
    }
}

// ---- one-time TM x 64 tile bf16 MFMA GEMM.
// EPI 0: store bf16 row-major (G). EPI 1: store f32 PERMUTED float4 (u).
template <int TM, int EPI>
__global__ __launch_bounds__(256) void gemm64(
        const unsigned short* __restrict__ A, int lda,
        const unsigned short* __restrict__ Bt, int ldb, int K,
        unsigned short* __restrict__ Cb, float* __restrict__ Cf, int ldc) {
    __shared__ alignas(16) unsigned short Al[2][TM * 64];
    __shared__ alignas(16) unsigned short Bl[2][64 * 64];
    const int t = threadIdx.x, w = t >> 6, lane = t & 63;
    const int m0 = blockIdx.y * TM, n0 = blockIdx.x * 64;
    constexpr int NJ = (TM == 64) ? 2 : 1;
    const int row_base = (TM == 64) ? (w >> 1) * 32 : 0;
    const int col_base = (TM == 64) ? (w & 1) * 32 : w * 16;

    f32x4 acc[2][NJ] = {};

    auto stage = [&](int buf, int k0) {
#pragma unroll
        for (int h = 0; h < 2; ++h) {
            const int c = h * 256 + t;
            const int row = c >> 3, g = c & 7;
            const int gl = g ^ (row & 7);
            gload_lds16(Bt + (size_t)(n0 + row) * ldb + k0 + gl * 8, &Bl[buf][(h * 256 + w * 64) * 8]);
        }
        if constexpr (TM == 64) {
#pragma unroll
            for (int h = 0; h < 2; ++h) {
                const int c = h * 256 + t;
                const int row = c >> 3, g = c & 7;
                const int gl = g ^ (row & 7);
                gload_lds16(A + (size_t)(m0 + row) * lda + k0 + gl * 8, &Al[buf][(h * 256 + w * 64) * 8]);
            }
        } else {
            const int row = t >> 3, g = t & 7;
            const int gl = g ^ (row & 7);
            gload_lds16(A + (size_t)(m0 + row) * lda + k0 + gl * 8, &Al[buf][(w * 64) * 8]);
        }
    };

    stage(0, 0);
    const int nK = K >> 6;
    for (int kt = 0; kt < nK; ++kt) {
        __syncthreads();
        const int cur = kt & 1;
        if (kt + 1 < nK) stage(cur ^ 1, (kt + 1) << 6);
        const unsigned short* a_base = Al[cur];
        const unsigned short* b_base = Bl[cur];
#pragma unroll
        for (int kh = 0; kh < 2; ++kh) {
            short8 av[2], bv[NJ];
#pragma unroll
            for (int i = 0; i < 2; ++i) {
                const int row = row_base + i * 16 + (lane & 15);
                const int g = (kh * 4 + (lane >> 4)) ^ (row & 7);
                av[i] = *(const short8*)(a_base + row * 64 + g * 8);
            }
#pragma unroll
            for (int j = 0; j < NJ; ++j) {
                const int row = col_base + j * 16 + (lane & 15);
                const int g = (kh * 4 + (lane >> 4)) ^ (row & 7);
                bv[j] = *(const short8*)(b_base + row * 64 + g * 8);
            }
#pragma unroll
            for (int i = 0; i < 2; ++i)
#pragma unroll
                for (int j = 0; j < NJ; ++j)
                    acc[i][j] = __builtin_amdgcn_mfma_f32_16x16x32_bf16(av[i], bv[j], acc[i][j], 0, 0, 0);
        }
    }

#pragma unroll
    for (int i = 0; i < 2; ++i)
#pragma unroll
        for (int j = 0; j < NJ; ++j) {
            const int col = n0 + col_base + j * 16 + (lane & 15);
            const int row0 = m0 + row_base + i * 16 + ((lane >> 4) << 2);
            if constexpr (EPI == 0) {
#pragma unroll
                for (int q = 0; q < 4; ++q)
                    Cb[(size_t)(row0 + q) * ldc + col] = f2bf(acc[i][j][q]);
            } else {
                float4 st;
                st.x = acc[i][j][0]; st.y = acc[i][j][1]; st.z = acc[i][j][2]; st.w = acc[i][j][3];
                *(float4*)(Cf + (((size_t)(row0 >> 2) * ldc + col) << 2)) = st;
            }
        }
}

// ---- loop kernel: A = fragment-blocked rbf, direct global->VGPR (coalesced);
// B = G LDS-staged 2-buf. 64x64 tile, 16 waves, 256 blocks.
// Wave = (quadrant qd = w&3) x (K-group gr = w>>2). vmcnt(4) counted waits.
__global__ __launch_bounds__(1024) void gemm_q(
        const unsigned short* __restrict__ Ain,   // bf16 r, FRAGMENT-BLOCKED
        const unsigned short* __restrict__ G,     // bf16 G (H x H), row-major
        float* __restrict__ rp,                   // f32 r, PERMUTED [row/4][col][4]
        unsigned* __restrict__ mv,                // packed m|v, PERMUTED
        const float* __restrict__ up,             // u, PERMUTED
        const float* __restrict__ bvec,
        unsigned short* __restrict__ rbf_out,     // FRAGMENT-BLOCKED; null on last iter
        float* __restrict__ out_r,                // row-major d_out (last iter only)
        float* __restrict__ lossPart,
        float inv1, float inv2) {
    __shared__ alignas(16) unsigned short Bb[2][4][4096];  // 64 KB: B, 2-buf x 4 groups
    __shared__ float scr[17408];                           // 68 KB: K-reduction scratch
    __shared__ float wred[16];
    const int t = threadIdx.x, w = t >> 6, lane = t & 63;
    const int bid = blockIdx.x;
    const int m0 = (bid >> 5) * 64;
    const int n0 = ((bid & 7) * 4 + ((bid >> 3) & 3)) * 64;   // XCD-pinned G panels
    const int qd = w & 3, gr = w >> 2;
    const int qrow = (qd >> 1) * 32, qcol = (qd & 1) * 32;
    const int rlo = lane & 15, hi = lane >> 4;

    // ---- epilogue-state prefetch: 4 VMEM issues (oldest in FIFO) ----
    const int col0 = n0 + qcol + (gr & 1) * 16 + rlo;
    const int rowb = m0 + qrow + (gr >> 1) * 16 + (hi << 2);   // 4-aligned
    const size_t pidx = ((size_t)(rowb >> 2) * H_SZ + col0) << 2;
    const float pre_b = bvec[col0];
    const float4 pre_r = *(const float4*)(rp + pidx);
    const float4 pre_u = *(const float4*)(up + pidx);
    const uint4 pre_mv = *(const uint4*)(mv + pidx);
    __builtin_amdgcn_sched_barrier(0);

    // ---- B staging (group-local, source XOR-swizzled) ----
    const int tt = t & 255;
    auto stageB = [&](int buf, int s) {
        const int kbase = gr * 512 + s * 64;
#pragma unroll
        for (int c = 0; c < 2; ++c) {
            const int idx = c * 256 + tt;
            const int row = idx >> 3, g = idx & 7;
            const int gl = g ^ (row & 7);
            gload_lds16(G + (size_t)(n0 + row) * H_SZ + kbase + gl * 8, &Bb[buf][gr][idx * 8]);
        }
    };

    // ---- A fragment loads: COALESCED (fragment-blocked layout).
    // fragment (fr = (m0+qrow)/16 + i, fk = gr*16 + s*2 + kh); lane-linear 1 KB.
    const int fr_base = (m0 + qrow) >> 4;
    short8 aF[3][2][2];
    auto loadA = [&](int slot, int s) {
#pragma unroll
        for (int i = 0; i < 2; ++i)
#pragma unroll
            for (int kh = 0; kh < 2; ++kh) {
                const size_t a = (((size_t)(fr_base + i) * 64 + gr * 16 + s * 2 + kh) * 64 + lane) * 8;
                aF[slot][i][kh] = *(const short8*)(Ain + a);
            }
    };

    // prologue FIFO: [epi(4)] [B0(2)] [A0(4)] [A1(4)]
    stageB(0, 0);
    __builtin_amdgcn_sched_barrier(0);
    loadA(0, 0);
    __builtin_amdgcn_sched_barrier(0);
    loadA(1, 1);
    __builtin_amdgcn_sched_barrier(0);

    f32x4 acc[2][2] = {};
#pragma unroll
    for (int s = 0; s < 8; ++s) {
        // steady: drain A(s)+B(s) (and epi at s=0), leave A(s+1)'s 4 loads.
        if (s < 7) asm volatile("s_waitcnt vmcnt(4) lgkmcnt(0)" ::: "memory");
        else       asm volatile("s_waitcnt vmcnt(0) lgkmcnt(0)" ::: "memory");
        __builtin_amdgcn_s_barrier();
        __builtin_amdgcn_sched_barrier(0);
        if (s + 1 < 8) stageB((s + 1) & 1, s + 1);
        __builtin_amdgcn_sched_barrier(0);
        if (s + 2 < 8) loadA((s + 2) % 3, s + 2);
        __builtin_amdgcn_sched_barrier(0);
        const unsigned short* b_base = Bb[s & 1][gr];
#pragma unroll
        for (int kh = 0; kh < 2; ++kh) {
            short8 bv[2];
#pragma unroll
            for (int j = 0; j < 2; ++j) {
                const int row = qcol + j * 16 + rlo;
                bv[j] = *(const short8*)(b_base + row * 64 + ((kh * 4 + hi) ^ (row & 7)) * 8);
            }
#pragma unroll
            for (int i = 0; i < 2; ++i)
#pragma unroll
                for (int j = 0; j < 2; ++j)
                    acc[i][j] = __builtin_amdgcn_mfma_f32_16x16x32_bf16(aF[s % 3][i][kh], bv[j], acc[i][j], 0, 0, 0);
        }
    }

    // ---- K-reduction via LDS scratch (stride 17: gcd(17,32)=1) ----
    __syncthreads();
    const int wbase = (w * 64 + lane) * 17;
#pragma unroll
    for (int i = 0; i < 2; ++i)
#pragma unroll
        for (int j = 0; j < 2; ++j)
#pragma unroll
            for (int q = 0; q < 4; ++q)
                scr[wbase + (i * 2 + j) * 4 + q] = acc[i][j][q];
    __syncthreads();

    float sval[4];
#pragma unroll
    for (int q = 0; q < 4; ++q) {
        float s = 0.f;
#pragma unroll
        for (int g = 0; g < 4; ++g)
            s += scr[((g * 4 + qd) * 64 + lane) * 17 + gr * 4 + q];
        sval[q] = s;
    }

    // ---- fused Adam + loss (state in registers; vector stores) ----
    const float prer[4] = {pre_r.x, pre_r.y, pre_r.z, pre_r.w};
    const float preu[4] = {pre_u.x, pre_u.y, pre_u.z, pre_u.w};
    const unsigned premv[4] = {pre_mv.x, pre_mv.y, pre_mv.z, pre_mv.w};
    float lpart = 0.f;
    float rn4[4];
    unsigned mv4[4];
#pragma unroll
    for (int q = 0; q < 4; ++q) {
        const float s = sval[q];
        const float rold = prer[q];
        const float ue = preu[q];
        const float g = (2.0f / B_SZ) * (rold - pre_b - ue + s);
        lpart += (rold - pre_b) * (rold - pre_b) + rold * (s - 2.0f * ue);
        const float m1 = 0.9f * bflo(premv[q]) + 0.1f * g;
        const float v1 = 0.999f * bfhi(premv[q]) + 0.001f * (g * g);
        mv4[q] = (unsigned)f2bf(m1) | ((unsigned)f2bf(v1) << 16);
        rn4[q] = rold - 0.01f * (m1 * inv1) / (sqrtf(v1 * inv2) + 1e-8f);
    }
    *(uint4*)(mv + pidx) = make_uint4(mv4[0], mv4[1], mv4[2], mv4[3]);
    if (rbf_out) {
        *(float4*)(rp + pidx) = make_float4(rn4[0], rn4[1], rn4[2], rn4[3]);
        // fragment-blocked rbf writes: lane index increments by 1 per q -> +8 elems
        const size_t fb = fidx(rowb, col0);
#pragma unroll
        for (int q = 0; q < 4; ++q)
            rbf_out[fb + (size_t)q * 8] = f2bf(rn4[q]);
    } else {
#pragma unroll
        for (int q = 0; q < 4; ++q)
            out_r[(size_t)(rowb + q) * H_SZ + col0] = rn4[q];
    }
#pragma unroll
    for (int off = 32; off > 0; off >>= 1) lpart += __shfl_down(lpart, off);
    if (lane == 0) wred[w] = lpart;
    __syncthreads();
    if (t == 0) {
        float sum = 0.f;
#pragma unroll
        for (int k = 0; k < 16; ++k) sum += wred[k];
        lossPart[bid] = sum;
    }
}

// ---- losses[t] = (sum of 256 lossPart + sum_b xc2) / B ----
__global__ __launch_bounds__(256) void k_finalize(const float* __restrict__ lossPart,
                                                  const float* __restrict__ xc2, float* __restrict__ out) {
    const int it = blockIdx.x, t = threadIdx.x;
    float p = lossPart[it * 256 + t] + xc2[t] + xc2[t + 256];
#pragma unroll
    for (int off = 32; off > 0; off >>= 1) p += __shfl_down(p, off);
    __shared__ float wred[4];
    if ((t & 63) == 0) wred[t >> 6] = p;
    __syncthreads();
    if (t == 0) out[(size_t)B_SZ * H_SZ + it] = (wred[0] + wred[1] + wred[2] + wred[3]) * (1.0f / B_SZ);
}

extern "C" void kernel_launch(void* const* d_in, const int* in_sizes, int n_in,
                              void* d_out, int out_size, void* d_ws, size_t ws_size,
                              hipStream_t stream) {
    const float* x = (const float*)d_in[0];
    const float* W = (const float*)d_in[1];
    const float* cvec = (const float*)d_in[2];
    const float* bvec = (const float*)d_in[3];
    const float* r0 = (const float*)d_in[4];
    float* out = (float*)d_out;
    char* ws = (char*)d_ws;

    unsigned short* Wt = (unsigned short*)(ws);              // 16 MB   (H x D bf16)
    unsigned short* Gbf = (unsigned short*)(ws + 16777216);  // 8 MB    (H x H bf16)
    unsigned short* xcbf = (unsigned short*)(ws + 25165824); // 4 MB    (B x D bf16)
    float* u = (float*)(ws + 29360128);                      // 4 MB    (B x H f32, permuted)
    float* r = (float*)(ws + 33554432);                      // 4 MB    (permuted)
    unsigned* mv = (unsigned*)(ws + 37748736);               // 4 MB    (bf16 m|v packed, permuted)
    unsigned short* rbfA = (unsigned short*)(ws + 41943040); // 2 MB    (fragment-blocked)
    unsigned short* rbfB = (unsigned short*)(ws + 44040192); // 2 MB
    float* xc2 = (float*)(ws + 46137344);                    // 2 KB
    float* lossPart = (float*)(ws + 46139392);               // 100 KB (ITERS x 256)

    k_transpose<<<dim3(64, 32), 256, 0, stream>>>(W, Wt);
    k_prepx<<<512, 256, 0, stream>>>(x, cvec, xcbf, xc2);
    k_init<<<1024, 256, 0, stream>>>(r0, r, mv, rbfA);
    // G = Wt @ Wt^T (W^T W), M=N=2048, K=4096 (1024 blocks, 4/CU)
    gemm64<64, 0><<<dim3(32, 32), 256, 0, stream>>>(Wt, D_SZ, Wt, D_SZ, D_SZ, Gbf, nullptr, H_SZ);
    // u = (x-c) @ W, M=512, N=2048, K=4096 (512 blocks, 2/CU) -> permuted store
    gemm64<32, 1><<<dim3(32, 16), 256, 0, stream>>>(xcbf, D_SZ, Wt, D_SZ, D_SZ, nullptr, u, H_SZ);

    for (int it = 0; it < ITERS; ++it) {
        const float inv1 = (float)(1.0 / (1.0 - std::pow(0.9, (double)(it + 1))));
        const float inv2 = (float)(1.0 / (1.0 - std::pow(0.999, (double)(it + 1))));
        const unsigned short* rin_bf = (it & 1) ? rbfB : rbfA;
        unsigned short* rout_bf = (it + 1 < ITERS) ? ((it & 1) ? rbfA : rbfB) : nullptr;
        gemm_q<<<256, 1024, 0, stream>>>(rin_bf, Gbf, r, mv, u, bvec, rout_bf, out,
                                         lossPart + (size_t)it * 256, inv1, inv2);
    }
    k_finalize<<<ITERS, 256, 0, stream>>>(lossPart, xc2, out);
}

// Round 22
// 1432.707 us; speedup vs baseline: 1.7114x; 1.0607x over previous
//
#include <hip/hip_runtime.h>
#include <cmath>

// Memory_76957224010242: 100-step Adam inference loop.
// G = W^T W, u = (x-c)@W once; per-iter s = r@G fused with Adam + loss.
// R22 = R16 (champion, 1429us) + symmetric-G: G-GEMM computes only n-tile >=
// m-tile (528/1024 blocks) and mirror-stores the transposed tile (bitwise-
// exact: both orientations evaluate sum_k Wt[i][k]Wt[j][k] in the same HW
// dot-product order). Loop kernel gemm_q byte-identical to R16.

#define B_SZ 512
#define H_SZ 2048
#define D_SZ 4096
#define ITERS 100

typedef __attribute__((ext_vector_type(8))) short short8;
typedef __attribute__((ext_vector_type(4))) float f32x4;

__device__ __forceinline__ unsigned short f2bf(float f) {
    unsigned u = __float_as_uint(f);
    u = (u + 0x7fffu + ((u >> 16) & 1u)) >> 16;  // RNE
    return (unsigned short)u;
}
__device__ __forceinline__ float bflo(unsigned mv) { return __uint_as_float(mv << 16); }
__device__ __forceinline__ float bfhi(unsigned mv) { return __uint_as_float(mv & 0xffff0000u); }

__device__ __forceinline__ void gload_lds16(const unsigned short* g, unsigned short* l) {
    __builtin_amdgcn_global_load_lds((const __attribute__((address_space(1))) void*)g,
                                     (__attribute__((address_space(3))) void*)l, 16, 0, 0);
}

// ---- W (D,H) f32 -> Wt (H,D) bf16 (transpose + cast) ----
__global__ __launch_bounds__(256) void k_transpose(const float* __restrict__ W,
                                                   unsigned short* __restrict__ Wt) {
    __shared__ unsigned short tile[64][72];
    const int d0 = blockIdx.x * 64, h0 = blockIdx.y * 64;
    const int t = threadIdx.x;
    const int lr = t >> 6, lc = t & 63;
#pragma unroll
    for (int rr = 0; rr < 16; ++rr) {
        const int dl = rr * 4 + lr;
        tile[dl][lc] = f2bf(W[(size_t)(d0 + dl) * H_SZ + h0 + lc]);
    }
    __syncthreads();
#pragma unroll
    for (int rr = 0; rr < 16; ++rr) {
        const int hl = rr * 4 + lr;
        Wt[(size_t)(h0 + hl) * D_SZ + d0 + lc] = tile[lc][hl];
    }
}

// ---- xc = (x - c) bf16, xc2[b] = sum_d (x-c)^2 ----
__global__ __launch_bounds__(256) void k_prepx(const float* __restrict__ x, const float* __restrict__ c,
                                               unsigned short* __restrict__ xcbf, float* __restrict__ xc2) {
    const int b = blockIdx.x, t = threadIdx.x;
    const float* xr = x + (size_t)b * D_SZ;
    unsigned short* orow = xcbf + (size_t)b * D_SZ;
    float acc = 0.f;
#pragma unroll
    for (int ch = 0; ch < 2; ++ch) {
        const int base = (ch * 256 + t) * 8;
        const float4 v0 = *(const float4*)(xr + base);
        const float4 v1 = *(const float4*)(xr + base + 4);
        const float4 c0 = *(const float4*)(c + base);
        const float4 c1 = *(const float4*)(c + base + 4);
        const float e0 = v0.x - c0.x, e1 = v0.y - c0.y, e2 = v0.z - c0.z, e3 = v0.w - c0.w;
        const float e4 = v1.x - c1.x, e5 = v1.y - c1.y, e6 = v1.z - c1.z, e7 = v1.w - c1.w;
        acc += e0 * e0 + e1 * e1 + e2 * e2 + e3 * e3 + e4 * e4 + e5 * e5 + e6 * e6 + e7 * e7;
        short8 ov;
        ov[0] = (short)f2bf(e0); ov[1] = (short)f2bf(e1); ov[2] = (short)f2bf(e2); ov[3] = (short)f2bf(e3);
        ov[4] = (short)f2bf(e4); ov[5] = (short)f2bf(e5); ov[6] = (short)f2bf(e6); ov[7] = (short)f2bf(e7);
        *(short8*)(orow + base) = ov;
    }
#pragma unroll
    for (int off = 32; off > 0; off >>= 1) acc += __shfl_down(acc, off);
    __shared__ float wred[4];
    if ((t & 63) == 0) wred[t >> 6] = acc;
    __syncthreads();
    if (t == 0) xc2[b] = wred[0] + wred[1] + wred[2] + wred[3];
}

// ---- r = r0; mv = 0; rbfA = bf16(r0) ----
__global__ __launch_bounds__(256) void k_init(const float* __restrict__ r0, float* __restrict__ r,
                                              unsigned* __restrict__ mv,
                                              unsigned short* __restrict__ rbfA) {
    const size_t i = (size_t)blockIdx.x * 256 + threadIdx.x;
#pragma unroll
    for (int k = 0; k < 4; ++k) {
        const size_t idx = i + (size_t)k * 262144;
        const float val = r0[idx];
        r[idx] = val; mv[idx] = 0u; rbfA[idx] = f2bf(val);
    }
}

// ---- symmetric G GEMM: G = Wt @ Wt^T, upper-triangle blocks + mirror store ----
__global__ __launch_bounds__(256) void gemm_sym(
        const unsigned short* __restrict__ A,     // Wt (H x D)
        unsigned short* __restrict__ Cb) {        // G (H x H)
    if (blockIdx.x < blockIdx.y) return;          // keep n-tile >= m-tile
    __shared__ alignas(16) unsigned short Al[2][64 * 64];
    __shared__ alignas(16) unsigned short Bl[2][64 * 64];
    const int t = threadIdx.x, w = t >> 6, lane = t & 63;
    const int m0 = blockIdx.y * 64, n0 = blockIdx.x * 64;
    const int row_base = (w >> 1) * 32;
    const int col_base = (w & 1) * 32;

    f32x4 acc[2][2] = {};

    auto stage = [&](int buf, int k0) {
#pragma unroll
        for (int h = 0; h < 2; ++h) {
            const int c = h * 256 + t;
            const int row = c >> 3, g = c & 7;
            const int gl = g ^ (row & 7);
            gload_lds16(A + (size_t)(n0 + row) * D_SZ + k0 + gl * 8, &Bl[buf][(h * 256 + w * 64) * 8]);
            gload_lds16(A + (size_t)(m0 + row) * D_SZ + k0 + gl * 8, &Al[buf][(h * 256 + w * 64) * 8]);
        }
    };

    stage(0, 0);
    for (int kt = 0; kt < 64; ++kt) {   // K = 4096, BK = 64
        __syncthreads();
        const int cur = kt & 1;
        if (kt + 1 < 64) stage(cur ^ 1, (kt + 1) << 6);
        const unsigned short* a_base = Al[cur];
        const unsigned short* b_base = Bl[cur];
#pragma unroll
        for (int kh = 0; kh < 2; ++kh) {
            short8 av[2], bv[2];
#pragma unroll
            for (int i = 0; i < 2; ++i) {
                const int row = row_base + i * 16 + (lane & 15);
                av[i] = *(const short8*)(a_base + row * 64 + ((kh * 4 + (lane >> 4)) ^ (row & 7)) * 8);
            }
#pragma unroll
            for (int j = 0; j < 2; ++j) {
                const int row = col_base + j * 16 + (lane & 15);
                bv[j] = *(const short8*)(b_base + row * 64 + ((kh * 4 + (lane >> 4)) ^ (row & 7)) * 8);
            }
#pragma unroll
            for (int i = 0; i < 2; ++i)
#pragma unroll
                for (int j = 0; j < 2; ++j)
                    acc[i][j] = __builtin_amdgcn_mfma_f32_16x16x32_bf16(av[i], bv[j], acc[i][j], 0, 0, 0);
        }
    }

    const bool offdiag = (n0 != m0);
#pragma unroll
    for (int i = 0; i < 2; ++i)
#pragma unroll
        for (int j = 0; j < 2; ++j) {
            const int col = n0 + col_base + j * 16 + (lane & 15);
            const int row0 = m0 + row_base + i * 16 + ((lane >> 4) << 2);
#pragma unroll
            for (int q = 0; q < 4; ++q) {
                const unsigned short v = f2bf(acc[i][j][q]);
                Cb[(size_t)(row0 + q) * H_SZ + col] = v;
                if (offdiag) Cb[(size_t)col * H_SZ + (row0 + q)] = v;  // mirror (bitwise-exact)
            }
        }
}

// ---- one-time u GEMM (TM=32, f32 row-major store) ----
__global__ __launch_bounds__(256) void gemm_u(
        const unsigned short* __restrict__ A,     // xcbf (B_SZ x D)
        const unsigned short* __restrict__ Bt,    // Wt (H x D)
        float* __restrict__ Cf) {                 // u (B_SZ x H)
    __shared__ alignas(16) unsigned short Al[2][32 * 64];
    __shared__ alignas(16) unsigned short Bl[2][64 * 64];
    const int t = threadIdx.x, w = t >> 6, lane = t & 63;
    const int m0 = blockIdx.y * 32, n0 = blockIdx.x * 64;
    const int col_base = w * 16;

    f32x4 acc[2] = {};

    auto stage = [&](int buf, int k0) {
#pragma unroll
        for (int h = 0; h < 2; ++h) {
            const int c = h * 256 + t;
            const int row = c >> 3, g = c & 7;
            const int gl = g ^ (row & 7);
            gload_lds16(Bt + (size_t)(n0 + row) * D_SZ + k0 + gl * 8, &Bl[buf][(h * 256 + w * 64) * 8]);
        }
        const int row = t >> 3, g = t & 7;
        const int gl = g ^ (row & 7);
        gload_lds16(A + (size_t)(m0 + row) * D_SZ + k0 + gl * 8, &Al[buf][(w * 64) * 8]);
    };

    stage(0, 0);
    for (int kt = 0; kt < 64; ++kt) {
        __syncthreads();
        const int cur = kt & 1;
        if (kt + 1 < 64) stage(cur ^ 1, (kt + 1) << 6);
        const unsigned short* a_base = Al[cur];
        const unsigned short* b_base = Bl[cur];
#pragma unroll
        for (int kh = 0; kh < 2; ++kh) {
            short8 av[2], bv;
#pragma unroll
            for (int i = 0; i < 2; ++i) {
                const int row = i * 16 + (lane & 15);
                av[i] = *(const short8*)(a_base + row * 64 + ((kh * 4 + (lane >> 4)) ^ (row & 7)) * 8);
            }
            {
                const int row = col_base + (lane & 15);
                bv = *(const short8*)(b_base + row * 64 + ((kh * 4 + (lane >> 4)) ^ (row & 7)) * 8);
            }
#pragma unroll
            for (int i = 0; i < 2; ++i)
                acc[i] = __builtin_amdgcn_mfma_f32_16x16x32_bf16(av[i], bv, acc[i], 0, 0, 0);
        }
    }

#pragma unroll
    for (int i = 0; i < 2; ++i) {
        const int col = n0 + col_base + (lane & 15);
        const int row0 = m0 + i * 16 + ((lane >> 4) << 2);
#pragma unroll
        for (int q = 0; q < 4; ++q)
            Cf[(size_t)(row0 + q) * H_SZ + col] = acc[i][q];
    }
}

// ---- loop kernel (byte-identical to R16): counted-vmcnt pipeline.
// 64x64 tile, 16 waves, 256 blocks. Wave = (quadrant qd = w&3) x (K-group gr = w>>2).
// A: 3 buffers, 2-deep prefetch. B: 2 buffers, 1-deep. Wait = vmcnt(2)+lgkmcnt(0).
__global__ __launch_bounds__(1024) void gemm_q(
        const unsigned short* __restrict__ Ain,   // bf16 r in (B_SZ x H)
        const unsigned short* __restrict__ G,     // bf16 G (H x H)
        const float* __restrict__ rin,
        float* __restrict__ rout,
        unsigned* __restrict__ mv,
        const float* __restrict__ ubuf,
        const float* __restrict__ bvec,
        unsigned short* __restrict__ rbf_out,     // null on last iter
        float* __restrict__ lossPart,
        float inv1, float inv2) {
    __shared__ alignas(16) unsigned short Ab[3][4][4096];  // 96 KB
    __shared__ alignas(16) unsigned short Bb[2][4][4096];  // 64 KB  (160 KB exact)
    const int t = threadIdx.x, w = t >> 6, lane = t & 63;
    const int bid = blockIdx.x;
    const int m0 = (bid >> 5) * 64;
    const int n0 = ((bid & 7) * 4 + ((bid >> 3) & 3)) * 64;   // XCD-pinned G panels
    const int qd = w & 3, gr = w >> 2;
    const int qrow = (qd >> 1) * 32, qcol = (qd & 1) * 32;
    const int rlo = lane & 15, hi = lane >> 4;

    // ---- epilogue-state prefetch (oldest in vmcnt FIFO; drained at step 0) ----
    const int col0 = n0 + qcol + (gr & 1) * 16 + rlo;
    const int rowb = m0 + qrow + (gr >> 1) * 16 + (hi << 2);
    float pre_r[4], pre_u[4];
    unsigned pre_mv[4];
    const float pre_b = bvec[col0];
#pragma unroll
    for (int q = 0; q < 4; ++q) {
        const size_t idx = (size_t)(rowb + q) * H_SZ + col0;
        pre_r[q] = rin[idx]; pre_u[q] = ubuf[idx]; pre_mv[q] = mv[idx];
    }
    __builtin_amdgcn_sched_barrier(0);

    // ---- staging: each group stages its own K-range; 2 loads/thread per stage ----
    const int tt = t & 255;
    auto stageA = [&](int buf, int s) {
        const int kbase = gr * 512 + s * 64;
#pragma unroll
        for (int c = 0; c < 2; ++c) {
            const int idx = c * 256 + tt;
            const int row = idx >> 3, g = idx & 7;
            const int gl = g ^ (row & 7);
            gload_lds16(Ain + (size_t)(m0 + row) * H_SZ + kbase + gl * 8, &Ab[buf][gr][idx * 8]);
        }
    };
    auto stageB = [&](int buf, int s) {
        const int kbase = gr * 512 + s * 64;
#pragma unroll
        for (int c = 0; c < 2; ++c) {
            const int idx = c * 256 + tt;
            const int row = idx >> 3, g = idx & 7;
            const int gl = g ^ (row & 7);
            gload_lds16(G + (size_t)(n0 + row) * H_SZ + kbase + gl * 8, &Bb[buf][gr][idx * 8]);
        }
    };

    // prologue FIFO: [epi..., A0, B0, A1]
    stageA(0, 0); stageB(0, 0); stageA(1, 1);

    f32x4 acc[2][2] = {};
    for (int s = 0; s < 8; ++s) {
        if (s < 7) asm volatile("s_waitcnt vmcnt(2) lgkmcnt(0)" ::: "memory");
        else       asm volatile("s_waitcnt vmcnt(0) lgkmcnt(0)" ::: "memory");
        __builtin_amdgcn_s_barrier();
        __builtin_amdgcn_sched_barrier(0);
        if (s + 1 < 8) stageB((s + 1) & 1, s + 1);
        if (s + 2 < 8) stageA((s + 2) % 3, s + 2);
        const unsigned short* a_base = Ab[s % 3][gr];
        const unsigned short* b_base = Bb[s & 1][gr];
#pragma unroll
        for (int kh = 0; kh < 2; ++kh) {
            short8 av[2], bv[2];
#pragma unroll
            for (int i = 0; i < 2; ++i) {
                const int row = qrow + i * 16 + rlo;
                av[i] = *(const short8*)(a_base + row * 64 + ((kh * 4 + hi) ^ (row & 7)) * 8);
            }
#pragma unroll
            for (int j = 0; j < 2; ++j) {
                const int row = qcol + j * 16 + rlo;
                bv[j] = *(const short8*)(b_base + row * 64 + ((kh * 4 + hi) ^ (row & 7)) * 8);
            }
#pragma unroll
            for (int i = 0; i < 2; ++i)
#pragma unroll
                for (int j = 0; j < 2; ++j)
                    acc[i][j] = __builtin_amdgcn_mfma_f32_16x16x32_bf16(av[i], bv[j], acc[i][j], 0, 0, 0);
        }
    }

    // ---- K-reduction via LDS scratch (aliases Ab; stride 17: gcd(17,32)=1).
    // Max scratch index 17406 floats; wred at float-ofs 20000 (Ab = 24576 floats).
    __syncthreads();
    float* scr = (float*)Ab;
    float* wred = scr + 20000;
    const int wbase = (w * 64 + lane) * 17;
#pragma unroll
    for (int i = 0; i < 2; ++i)
#pragma unroll
        for (int j = 0; j < 2; ++j)
#pragma unroll
            for (int q = 0; q < 4; ++q)
                scr[wbase + (i * 2 + j) * 4 + q] = acc[i][j][q];
    __syncthreads();

    float sval[4];
#pragma unroll
    for (int q = 0; q < 4; ++q) {
        float s = 0.f;
#pragma unroll
        for (int g = 0; g < 4; ++g)
            s += scr[((g * 4 + qd) * 64 + lane) * 17 + gr * 4 + q];
        sval[q] = s;
    }

    // ---- fused Adam + loss (state already in registers) ----
    float lpart = 0.f;
#pragma unroll
    for (int q = 0; q < 4; ++q) {
        const size_t idx = (size_t)(rowb + q) * H_SZ + col0;
        const float s = sval[q];
        const float rold = pre_r[q];
        const float ue = pre_u[q];
        const float g = (2.0f / B_SZ) * (rold - pre_b - ue + s);
        lpart += (rold - pre_b) * (rold - pre_b) + rold * (s - 2.0f * ue);
        const float m1 = 0.9f * bflo(pre_mv[q]) + 0.1f * g;
        const float v1 = 0.999f * bfhi(pre_mv[q]) + 0.001f * (g * g);
        mv[idx] = (unsigned)f2bf(m1) | ((unsigned)f2bf(v1) << 16);
        const float rn = rold - 0.01f * (m1 * inv1) / (sqrtf(v1 * inv2) + 1e-8f);
        rout[idx] = rn;
        if (rbf_out) rbf_out[idx] = f2bf(rn);
    }
#pragma unroll
    for (int off = 32; off > 0; off >>= 1) lpart += __shfl_down(lpart, off);
    if (lane == 0) wred[w] = lpart;
    __syncthreads();
    if (t == 0) {
        float sum = 0.f;
#pragma unroll
        for (int k = 0; k < 16; ++k) sum += wred[k];
        lossPart[bid] = sum;
    }
}

// ---- losses[t] = (sum of 256 lossPart + sum_b xc2) / B ----
__global__ __launch_bounds__(256) void k_finalize(const float* __restrict__ lossPart,
                                                  const float* __restrict__ xc2, float* __restrict__ out) {
    const int it = blockIdx.x, t = threadIdx.x;
    float p = lossPart[it * 256 + t] + xc2[t] + xc2[t + 256];
#pragma unroll
    for (int off = 32; off > 0; off >>= 1) p += __shfl_down(p, off);
    __shared__ float wred[4];
    if ((t & 63) == 0) wred[t >> 6] = p;
    __syncthreads();
    if (t == 0) out[(size_t)B_SZ * H_SZ + it] = (wred[0] + wred[1] + wred[2] + wred[3]) * (1.0f / B_SZ);
}

extern "C" void kernel_launch(void* const* d_in, const int* in_sizes, int n_in,
                              void* d_out, int out_size, void* d_ws, size_t ws_size,
                              hipStream_t stream) {
    const float* x = (const float*)d_in[0];
    const float* W = (const float*)d_in[1];
    const float* cvec = (const float*)d_in[2];
    const float* bvec = (const float*)d_in[3];
    const float* r0 = (const float*)d_in[4];
    float* out = (float*)d_out;
    char* ws = (char*)d_ws;

    unsigned short* Wt = (unsigned short*)(ws);              // 16 MB   (H x D bf16)
    unsigned short* Gbf = (unsigned short*)(ws + 16777216);  // 8 MB    (H x H bf16)
    unsigned short* xcbf = (unsigned short*)(ws + 25165824); // 4 MB    (B x D bf16)
    float* u = (float*)(ws + 29360128);                      // 4 MB    (B x H f32)
    float* r = (float*)(ws + 33554432);                      // 4 MB
    unsigned* mv = (unsigned*)(ws + 37748736);               // 4 MB    (bf16 m | bf16 v packed)
    unsigned short* rbfA = (unsigned short*)(ws + 41943040); // 2 MB
    unsigned short* rbfB = (unsigned short*)(ws + 44040192); // 2 MB
    float* xc2 = (float*)(ws + 46137344);                    // 2 KB
    float* lossPart = (float*)(ws + 46139392);               // 100 KB (ITERS x 256)

    k_transpose<<<dim3(64, 32), 256, 0, stream>>>(W, Wt);
    k_prepx<<<512, 256, 0, stream>>>(x, cvec, xcbf, xc2);
    k_init<<<1024, 256, 0, stream>>>(r0, r, mv, rbfA);
    // G = Wt @ Wt^T (W^T W), symmetric: upper-triangle blocks + mirror store
    gemm_sym<<<dim3(32, 32), 256, 0, stream>>>(Wt, Gbf);
    // u = (x-c) @ W, M=512, N=2048, K=4096 (512 blocks, 2/CU)
    gemm_u<<<dim3(32, 16), 256, 0, stream>>>(xcbf, Wt, u);

    for (int it = 0; it < ITERS; ++it) {
        const float inv1 = (float)(1.0 / (1.0 - std::pow(0.9, (double)(it + 1))));
        const float inv2 = (float)(1.0 / (1.0 - std::pow(0.999, (double)(it + 1))));
        const unsigned short* rin_bf = (it & 1) ? rbfB : rbfA;
        unsigned short* rout_bf = (it + 1 < ITERS) ? ((it & 1) ? rbfA : rbfB) : nullptr;
        float* rout_f = (it + 1 < ITERS) ? r : out;  // last iter writes f32 r into d_out
        gemm_q<<<256, 1024, 0, stream>>>(rin_bf, Gbf, r, rout_f, mv, u, bvec, rout_bf,
                                         lossPart + (size_t)it * 256, inv1, inv2);
    }
    k_finalize<<<ITERS, 256, 0, stream>>>(lossPart, xc2, out);
}

// Round 23
// 1429.811 us; speedup vs baseline: 1.7149x; 1.0020x over previous
//
#include <hip/hip_runtime.h>
#include <cmath>

// Memory_76957224010242: 100-step Adam inference loop.
// G = W^T W, u = (x-c)@W once; per-iter s = r@G fused with Adam + loss.
// R23 = R16 champion, byte-identical (1429 us, absmax 0.01171875).
// Loop kernel: 64x64 tile, 16 waves (4/SIMD), 256 blocks, wave = quadrant x
// K-group, A 3-buf/2-deep + B 2-buf/1-deep counted-vmcnt pipeline
// (vmcnt(2)+s_barrier per K-step), LDS-scratch K-reduction, fused Adam + loss.

#define B_SZ 512
#define H_SZ 2048
#define D_SZ 4096
#define ITERS 100

typedef __attribute__((ext_vector_type(8))) short short8;
typedef __attribute__((ext_vector_type(4))) float f32x4;

__device__ __forceinline__ unsigned short f2bf(float f) {
    unsigned u = __float_as_uint(f);
    u = (u + 0x7fffu + ((u >> 16) & 1u)) >> 16;  // RNE
    return (unsigned short)u;
}
__device__ __forceinline__ float bflo(unsigned mv) { return __uint_as_float(mv << 16); }
__device__ __forceinline__ float bfhi(unsigned mv) { return __uint_as_float(mv & 0xffff0000u); }

__device__ __forceinline__ void gload_lds16(const unsigned short* g, unsigned short* l) {
    __builtin_amdgcn_global_load_lds((const __attribute__((address_space(1))) void*)g,
                                     (__attribute__((address_space(3))) void*)l, 16, 0, 0);
}

// ---- W (D,H) f32 -> Wt (H,D) bf16 (transpose + cast) ----
__global__ __launch_bounds__(256) void k_transpose(const float* __restrict__ W,
                                                   unsigned short* __restrict__ Wt) {
    __shared__ unsigned short tile[64][72];
    const int d0 = blockIdx.x * 64, h0 = blockIdx.y * 64;
    const int t = threadIdx.x;
    const int lr = t >> 6, lc = t & 63;
#pragma unroll
    for (int rr = 0; rr < 16; ++rr) {
        const int dl = rr * 4 + lr;
        tile[dl][lc] = f2bf(W[(size_t)(d0 + dl) * H_SZ + h0 + lc]);
    }
    __syncthreads();
#pragma unroll
    for (int rr = 0; rr < 16; ++rr) {
        const int hl = rr * 4 + lr;
        Wt[(size_t)(h0 + hl) * D_SZ + d0 + lc] = tile[lc][hl];
    }
}

// ---- xc = (x - c) bf16, xc2[b] = sum_d (x-c)^2 ----
__global__ __launch_bounds__(256) void k_prepx(const float* __restrict__ x, const float* __restrict__ c,
                                               unsigned short* __restrict__ xcbf, float* __restrict__ xc2) {
    const int b = blockIdx.x, t = threadIdx.x;
    const float* xr = x + (size_t)b * D_SZ;
    unsigned short* orow = xcbf + (size_t)b * D_SZ;
    float acc = 0.f;
#pragma unroll
    for (int ch = 0; ch < 2; ++ch) {
        const int base = (ch * 256 + t) * 8;
        const float4 v0 = *(const float4*)(xr + base);
        const float4 v1 = *(const float4*)(xr + base + 4);
        const float4 c0 = *(const float4*)(c + base);
        const float4 c1 = *(const float4*)(c + base + 4);
        const float e0 = v0.x - c0.x, e1 = v0.y - c0.y, e2 = v0.z - c0.z, e3 = v0.w - c0.w;
        const float e4 = v1.x - c1.x, e5 = v1.y - c1.y, e6 = v1.z - c1.z, e7 = v1.w - c1.w;
        acc += e0 * e0 + e1 * e1 + e2 * e2 + e3 * e3 + e4 * e4 + e5 * e5 + e6 * e6 + e7 * e7;
        short8 ov;
        ov[0] = (short)f2bf(e0); ov[1] = (short)f2bf(e1); ov[2] = (short)f2bf(e2); ov[3] = (short)f2bf(e3);
        ov[4] = (short)f2bf(e4); ov[5] = (short)f2bf(e5); ov[6] = (short)f2bf(e6); ov[7] = (short)f2bf(e7);
        *(short8*)(orow + base) = ov;
    }
#pragma unroll
    for (int off = 32; off > 0; off >>= 1) acc += __shfl_down(acc, off);
    __shared__ float wred[4];
    if ((t & 63) == 0) wred[t >> 6] = acc;
    __syncthreads();
    if (t == 0) xc2[b] = wred[0] + wred[1] + wred[2] + wred[3];
}

// ---- r = r0; mv = 0; rbfA = bf16(r0) ----
__global__ __launch_bounds__(256) void k_init(const float* __restrict__ r0, float* __restrict__ r,
                                              unsigned* __restrict__ mv,
                                              unsigned short* __restrict__ rbfA) {
    const size_t i = (size_t)blockIdx.x * 256 + threadIdx.x;
#pragma unroll
    for (int k = 0; k < 4; ++k) {
        const size_t idx = i + (size_t)k * 262144;
        const float val = r0[idx];
        r[idx] = val; mv[idx] = 0u; rbfA[idx] = f2bf(val);
    }
}

// ---- one-time TM x 64 tile bf16 MFMA GEMM (EPI 0: bf16 store; EPI 1: f32 store) ----
template <int TM, int EPI>
__global__ __launch_bounds__(256) void gemm64(
        const unsigned short* __restrict__ A, int lda,
        const unsigned short* __restrict__ Bt, int ldb, int K,
        unsigned short* __restrict__ Cb, float* __restrict__ Cf, int ldc) {
    __shared__ alignas(16) unsigned short Al[2][TM * 64];
    __shared__ alignas(16) unsigned short Bl[2][64 * 64];
    const int t = threadIdx.x, w = t >> 6, lane = t & 63;
    const int m0 = blockIdx.y * TM, n0 = blockIdx.x * 64;
    constexpr int NJ = (TM == 64) ? 2 : 1;
    const int row_base = (TM == 64) ? (w >> 1) * 32 : 0;
    const int col_base = (TM == 64) ? (w & 1) * 32 : w * 16;

    f32x4 acc[2][NJ] = {};

    auto stage = [&](int buf, int k0) {
#pragma unroll
        for (int h = 0; h < 2; ++h) {
            const int c = h * 256 + t;
            const int row = c >> 3, g = c & 7;
            const int gl = g ^ (row & 7);
            gload_lds16(Bt + (size_t)(n0 + row) * ldb + k0 + gl * 8, &Bl[buf][(h * 256 + w * 64) * 8]);
        }
        if constexpr (TM == 64) {
#pragma unroll
            for (int h = 0; h < 2; ++h) {
                const int c = h * 256 + t;
                const int row = c >> 3, g = c & 7;
                const int gl = g ^ (row & 7);
                gload_lds16(A + (size_t)(m0 + row) * lda + k0 + gl * 8, &Al[buf][(h * 256 + w * 64) * 8]);
            }
        } else {
            const int row = t >> 3, g = t & 7;
            const int gl = g ^ (row & 7);
            gload_lds16(A + (size_t)(m0 + row) * lda + k0 + gl * 8, &Al[buf][(w * 64) * 8]);
        }
    };

    stage(0, 0);
    const int nK = K >> 6;
    for (int kt = 0; kt < nK; ++kt) {
        __syncthreads();
        const int cur = kt & 1;
        if (kt + 1 < nK) stage(cur ^ 1, (kt + 1) << 6);
        const unsigned short* a_base = Al[cur];
        const unsigned short* b_base = Bl[cur];
#pragma unroll
        for (int kh = 0; kh < 2; ++kh) {
            short8 av[2], bv[NJ];
#pragma unroll
            for (int i = 0; i < 2; ++i) {
                const int row = row_base + i * 16 + (lane & 15);
                const int g = (kh * 4 + (lane >> 4)) ^ (row & 7);
                av[i] = *(const short8*)(a_base + row * 64 + g * 8);
            }
#pragma unroll
            for (int j = 0; j < NJ; ++j) {
                const int row = col_base + j * 16 + (lane & 15);
                const int g = (kh * 4 + (lane >> 4)) ^ (row & 7);
                bv[j] = *(const short8*)(b_base + row * 64 + g * 8);
            }
#pragma unroll
            for (int i = 0; i < 2; ++i)
#pragma unroll
                for (int j = 0; j < NJ; ++j)
                    acc[i][j] = __builtin_amdgcn_mfma_f32_16x16x32_bf16(av[i], bv[j], acc[i][j], 0, 0, 0);
        }
    }

#pragma unroll
    for (int i = 0; i < 2; ++i)
#pragma unroll
        for (int j = 0; j < NJ; ++j) {
            const int col = n0 + col_base + j * 16 + (lane & 15);
            const int row0 = m0 + row_base + i * 16 + ((lane >> 4) << 2);
#pragma unroll
            for (int q = 0; q < 4; ++q) {
                if constexpr (EPI == 0) Cb[(size_t)(row0 + q) * ldc + col] = f2bf(acc[i][j][q]);
                else Cf[(size_t)(row0 + q) * ldc + col] = acc[i][j][q];
            }
        }
}

// ---- loop kernel: counted-vmcnt pipeline.
// 64x64 tile, 16 waves, 256 blocks. Wave = (quadrant qd = w&3) x (K-group gr = w>>2).
// A: 3 buffers, 2-deep prefetch. B: 2 buffers, 1-deep. Wait = vmcnt(2)+lgkmcnt(0).
__global__ __launch_bounds__(1024) void gemm_q(
        const unsigned short* __restrict__ Ain,   // bf16 r in (B_SZ x H)
        const unsigned short* __restrict__ G,     // bf16 G (H x H)
        const float* __restrict__ rin,
        float* __restrict__ rout,
        unsigned* __restrict__ mv,
        const float* __restrict__ ubuf,
        const float* __restrict__ bvec,
        unsigned short* __restrict__ rbf_out,     // null on last iter
        float* __restrict__ lossPart,
        float inv1, float inv2) {
    __shared__ alignas(16) unsigned short Ab[3][4][4096];  // 96 KB: A, 3-buf x 4 groups
    __shared__ alignas(16) unsigned short Bb[2][4][4096];  // 64 KB: B, 2-buf x 4 groups
    // LDS total = 160 KB exactly. Loss-reduction wred aliased into Ab scratch below.
    const int t = threadIdx.x, w = t >> 6, lane = t & 63;
    const int bid = blockIdx.x;
    const int m0 = (bid >> 5) * 64;
    const int n0 = ((bid & 7) * 4 + ((bid >> 3) & 3)) * 64;   // XCD-pinned G panels
    const int qd = w & 3, gr = w >> 2;
    const int qrow = (qd >> 1) * 32, qcol = (qd & 1) * 32;
    const int rlo = lane & 15, hi = lane >> 4;

    // ---- epilogue-state prefetch (oldest in vmcnt FIFO; drained at step 0) ----
    const int col0 = n0 + qcol + (gr & 1) * 16 + rlo;
    const int rowb = m0 + qrow + (gr >> 1) * 16 + (hi << 2);
    float pre_r[4], pre_u[4];
    unsigned pre_mv[4];
    const float pre_b = bvec[col0];
#pragma unroll
    for (int q = 0; q < 4; ++q) {
        const size_t idx = (size_t)(rowb + q) * H_SZ + col0;
        pre_r[q] = rin[idx]; pre_u[q] = ubuf[idx]; pre_mv[q] = mv[idx];
    }
    __builtin_amdgcn_sched_barrier(0);

    // ---- staging: each group stages its own K-range; 2 loads/thread per stage ----
    const int tt = t & 255;
    auto stageA = [&](int buf, int s) {
        const int kbase = gr * 512 + s * 64;
#pragma unroll
        for (int c = 0; c < 2; ++c) {
            const int idx = c * 256 + tt;
            const int row = idx >> 3, g = idx & 7;
            const int gl = g ^ (row & 7);
            gload_lds16(Ain + (size_t)(m0 + row) * H_SZ + kbase + gl * 8, &Ab[buf][gr][idx * 8]);
        }
    };
    auto stageB = [&](int buf, int s) {
        const int kbase = gr * 512 + s * 64;
#pragma unroll
        for (int c = 0; c < 2; ++c) {
            const int idx = c * 256 + tt;
            const int row = idx >> 3, g = idx & 7;
            const int gl = g ^ (row & 7);
            gload_lds16(G + (size_t)(n0 + row) * H_SZ + kbase + gl * 8, &Bb[buf][gr][idx * 8]);
        }
    };

    // prologue FIFO: [epi..., A0, B0, A1]
    stageA(0, 0); stageB(0, 0); stageA(1, 1);

    f32x4 acc[2][2] = {};
    for (int s = 0; s < 8; ++s) {
        // steady: drain thru B(s) (leaves A(s+1)'s 2 loads); last step drains all.
        if (s < 7) asm volatile("s_waitcnt vmcnt(2) lgkmcnt(0)" ::: "memory");
        else       asm volatile("s_waitcnt vmcnt(0) lgkmcnt(0)" ::: "memory");
        __builtin_amdgcn_s_barrier();
        __builtin_amdgcn_sched_barrier(0);
        if (s + 1 < 8) stageB((s + 1) & 1, s + 1);
        if (s + 2 < 8) stageA((s + 2) % 3, s + 2);
        const unsigned short* a_base = Ab[s % 3][gr];
        const unsigned short* b_base = Bb[s & 1][gr];
#pragma unroll
        for (int kh = 0; kh < 2; ++kh) {
            short8 av[2], bv[2];
#pragma unroll
            for (int i = 0; i < 2; ++i) {
                const int row = qrow + i * 16 + rlo;
                av[i] = *(const short8*)(a_base + row * 64 + ((kh * 4 + hi) ^ (row & 7)) * 8);
            }
#pragma unroll
            for (int j = 0; j < 2; ++j) {
                const int row = qcol + j * 16 + rlo;
                bv[j] = *(const short8*)(b_base + row * 64 + ((kh * 4 + hi) ^ (row & 7)) * 8);
            }
#pragma unroll
            for (int i = 0; i < 2; ++i)
#pragma unroll
                for (int j = 0; j < 2; ++j)
                    acc[i][j] = __builtin_amdgcn_mfma_f32_16x16x32_bf16(av[i], bv[j], acc[i][j], 0, 0, 0);
        }
    }

    // ---- K-reduction via LDS scratch (aliases Ab; stride 17: gcd(17,32)=1).
    // Max scratch index (1023*17+15) = 17406 floats; wred at ofs 20000 (Ab holds 24576 floats).
    __syncthreads();  // all reads + staged writes complete before overwrite
    float* scr = (float*)Ab;
    float* wred = scr + 20000;
    const int wbase = (w * 64 + lane) * 17;
#pragma unroll
    for (int i = 0; i < 2; ++i)
#pragma unroll
        for (int j = 0; j < 2; ++j)
#pragma unroll
            for (int q = 0; q < 4; ++q)
                scr[wbase + (i * 2 + j) * 4 + q] = acc[i][j][q];
    __syncthreads();

    float sval[4];
#pragma unroll
    for (int q = 0; q < 4; ++q) {
        float s = 0.f;
#pragma unroll
        for (int g = 0; g < 4; ++g)
            s += scr[((g * 4 + qd) * 64 + lane) * 17 + gr * 4 + q];
        sval[q] = s;
    }

    // ---- fused Adam + loss (state already in registers) ----
    float lpart = 0.f;
#pragma unroll
    for (int q = 0; q < 4; ++q) {
        const size_t idx = (size_t)(rowb + q) * H_SZ + col0;
        const float s = sval[q];
        const float rold = pre_r[q];
        const float ue = pre_u[q];
        const float g = (2.0f / B_SZ) * (rold - pre_b - ue + s);
        lpart += (rold - pre_b) * (rold - pre_b) + rold * (s - 2.0f * ue);
        const float m1 = 0.9f * bflo(pre_mv[q]) + 0.1f * g;
        const float v1 = 0.999f * bfhi(pre_mv[q]) + 0.001f * (g * g);
        mv[idx] = (unsigned)f2bf(m1) | ((unsigned)f2bf(v1) << 16);
        const float rn = rold - 0.01f * (m1 * inv1) / (sqrtf(v1 * inv2) + 1e-8f);
        rout[idx] = rn;
        if (rbf_out) rbf_out[idx] = f2bf(rn);
    }
#pragma unroll
    for (int off = 32; off > 0; off >>= 1) lpart += __shfl_down(lpart, off);
    if (lane == 0) wred[w] = lpart;
    __syncthreads();
    if (t == 0) {
        float sum = 0.f;
#pragma unroll
        for (int k = 0; k < 16; ++k) sum += wred[k];
        lossPart[bid] = sum;
    }
}

// ---- losses[t] = (sum of 256 lossPart + sum_b xc2) / B ----
__global__ __launch_bounds__(256) void k_finalize(const float* __restrict__ lossPart,
                                                  const float* __restrict__ xc2, float* __restrict__ out) {
    const int it = blockIdx.x, t = threadIdx.x;
    float p = lossPart[it * 256 + t] + xc2[t] + xc2[t + 256];
#pragma unroll
    for (int off = 32; off > 0; off >>= 1) p += __shfl_down(p, off);
    __shared__ float wred[4];
    if ((t & 63) == 0) wred[t >> 6] = p;
    __syncthreads();
    if (t == 0) out[(size_t)B_SZ * H_SZ + it] = (wred[0] + wred[1] + wred[2] + wred[3]) * (1.0f / B_SZ);
}

extern "C" void kernel_launch(void* const* d_in, const int* in_sizes, int n_in,
                              void* d_out, int out_size, void* d_ws, size_t ws_size,
                              hipStream_t stream) {
    const float* x = (const float*)d_in[0];
    const float* W = (const float*)d_in[1];
    const float* cvec = (const float*)d_in[2];
    const float* bvec = (const float*)d_in[3];
    const float* r0 = (const float*)d_in[4];
    float* out = (float*)d_out;
    char* ws = (char*)d_ws;

    unsigned short* Wt = (unsigned short*)(ws);              // 16 MB   (H x D bf16)
    unsigned short* Gbf = (unsigned short*)(ws + 16777216);  // 8 MB    (H x H bf16)
    unsigned short* xcbf = (unsigned short*)(ws + 25165824); // 4 MB    (B x D bf16)
    float* u = (float*)(ws + 29360128);                      // 4 MB    (B x H f32)
    float* r = (float*)(ws + 33554432);                      // 4 MB
    unsigned* mv = (unsigned*)(ws + 37748736);               // 4 MB    (bf16 m | bf16 v packed)
    unsigned short* rbfA = (unsigned short*)(ws + 41943040); // 2 MB
    unsigned short* rbfB = (unsigned short*)(ws + 44040192); // 2 MB
    float* xc2 = (float*)(ws + 46137344);                    // 2 KB
    float* lossPart = (float*)(ws + 46139392);               // 100 KB (ITERS x 256)

    k_transpose<<<dim3(64, 32), 256, 0, stream>>>(W, Wt);
    k_prepx<<<512, 256, 0, stream>>>(x, cvec, xcbf, xc2);
    k_init<<<1024, 256, 0, stream>>>(r0, r, mv, rbfA);
    // G = Wt @ Wt^T (W^T W), M=N=2048, K=4096 (1024 blocks, 4/CU)
    gemm64<64, 0><<<dim3(32, 32), 256, 0, stream>>>(Wt, D_SZ, Wt, D_SZ, D_SZ, Gbf, nullptr, H_SZ);
    // u = (x-c) @ W, M=512, N=2048, K=4096 (512 blocks, 2/CU)
    gemm64<32, 1><<<dim3(32, 16), 256, 0, stream>>>(xcbf, D_SZ, Wt, D_SZ, D_SZ, nullptr, u, H_SZ);

    for (int it = 0; it < ITERS; ++it) {
        const float inv1 = (float)(1.0 / (1.0 - std::pow(0.9, (double)(it + 1))));
        const float inv2 = (float)(1.0 / (1.0 - std::pow(0.999, (double)(it + 1))));
        const unsigned short* rin_bf = (it & 1) ? rbfB : rbfA;
        unsigned short* rout_bf = (it + 1 < ITERS) ? ((it & 1) ? rbfA : rbfB) : nullptr;
        float* rout_f = (it + 1 < ITERS) ? r : out;  // last iter writes f32 r into d_out
        gemm_q<<<256, 1024, 0, stream>>>(rin_bf, Gbf, r, rout_f, mv, u, bvec, rout_bf,
                                         lossPart + (size_t)it * 256, inv1, inv2);
    }
    k_finalize<<<ITERS, 256, 0, stream>>>(lossPart, xc2, out);
}